// Round 7
// baseline (293.366 us; speedup 1.0000x reference)
//
#include <hip/hip_runtime.h>

// ConvCapsMatrix EM routing, MI355X. Inputs FP32, output FP32.
// R24: tail elimination. R21 j-body (pk, no pipeline) with 384-thread blocks:
// LDS 30.1KB, 5 blocks/CU (threads 1920<=2048, VGPR 5*384*68<=131072, LDS
// 5*30.1<=160) -> 1280 resident slots >= 1152 blocks -> ALL stats blocks run
// in ONE round. The old 512-thread grid had 1152 = 1024 slots + 128-block
// straggler round at 1 block/CU (latency-bound, ~1/3 of wall) - explains the
// chronic ~30% occupancy and per-block wall >> issue time.
// Post-mortem R23: pipeline refill -> VGPR 68 = 4 over the 64 cliff ->
// occupancy halved (17.6%), stats 51.7us. No spills. The >=65-reg bracket at
// 512 threads means 2 blocks/CU; at 384 threads the bracket boundary is 68.
// ng = 12 groups, j = 12 iters (144 n/block unchanged); 6-wave epilogue.
// __launch_bounds__(384,5): min-blocks/CU semantics (R20-confirmed) -> cap 68.
// GUARDRAIL: VGPR<=68, WRITE_SIZE ~4752KB/launch; 87MB-class => spill abort.

#define EPSV 1e-8f

typedef float v2f __attribute__((ext_vector_type(2)));
typedef float v4f __attribute__((ext_vector_type(4)));

// packed 2xf32 ops (VOP3P). Default modifiers = normal packed lanes.
#define PK_ADD(d, a, b) asm("v_pk_add_f32 %0, %1, %2" : "=v"(d) : "v"(a), "v"(b))
#define PK_MUL(d, a, b) asm("v_pk_mul_f32 %0, %1, %2" : "=v"(d) : "v"(a), "v"(b))
#define PK_FMA_ACC(acc, a, b) \
  asm("v_pk_fma_f32 %0, %1, %2, %0" : "+v"(acc) : "v"(a), "v"(b))
// src0 broadcast from lo / hi dword of the pair (op_sel per-src dword select)
#define PK_MUL_BLO(d, a, b) \
  asm("v_pk_mul_f32 %0, %1, %2 op_sel:[0,0] op_sel_hi:[0,1]" : "=v"(d) : "v"(a), "v"(b))
#define PK_FMA_BLO_ACC(acc, a, b) \
  asm("v_pk_fma_f32 %0, %1, %2, %0 op_sel:[0,0,0] op_sel_hi:[0,1,1]" : "+v"(acc) : "v"(a), "v"(b))
#define PK_FMA_BHI_ACC(acc, a, b) \
  asm("v_pk_fma_f32 %0, %1, %2, %0 op_sel:[1,0,0] op_sel_hi:[1,1,1]" : "+v"(acc) : "v"(a), "v"(b))

template <int CTRL>
__device__ __forceinline__ float dppf(float v) {
  return __int_as_float(__builtin_amdgcn_update_dpp(
      0, __float_as_int(v), CTRL, 0xf, 0xf, true));
}
__device__ __forceinline__ float swz16(float v) {   // lane ^ 16 within 32-groups
  return __int_as_float(__builtin_amdgcn_ds_swizzle(__float_as_int(v), 0x401F));
}
__device__ __forceinline__ float red_max32(float v) {
  v = fmaxf(v, dppf<0xB1>(v));
  v = fmaxf(v, dppf<0x4E>(v));
  v = fmaxf(v, dppf<0x141>(v));
  v = fmaxf(v, dppf<0x140>(v));
  v = fmaxf(v, swz16(v));
  return v;
}
__device__ __forceinline__ float red_sum32(float v) {
  v += dppf<0xB1>(v);
  v += dppf<0x4E>(v);
  v += dppf<0x141>(v);
  v += dppf<0x140>(v);
  v += swz16(v);
  return v;
}

// V2[xi*2+zp] lanes (z=2zp, 2zp+1) = sum_y xv[xi*4+y] * Wf[y*4+z]
__device__ __forceinline__ void compute_votes_pk(const float* __restrict__ Wt,
                                                 const float* __restrict__ xr,
                                                 int n, int o, v2f* __restrict__ V2)
{
  v2f Wf2[8];
  {
    const float* wp = Wt + (((n << 5) + o) << 4);
#pragma unroll
    for (int i = 0; i < 4; ++i) {
      const v4f q = *(const v4f*)(wp + (i << 2));
      Wf2[i*2+0] = __builtin_shufflevector(q, q, 0, 1);
      Wf2[i*2+1] = __builtin_shufflevector(q, q, 2, 3);
    }
  }
  v2f xv2[8];
#pragma unroll
  for (int i = 0; i < 4; ++i) {
    const v4f q = *(const v4f*)(xr + (i << 2));
    xv2[i*2+0] = __builtin_shufflevector(q, q, 0, 1);
    xv2[i*2+1] = __builtin_shufflevector(q, q, 2, 3);
  }
#pragma unroll
  for (int xi = 0; xi < 4; ++xi) {
#pragma unroll
    for (int zp = 0; zp < 2; ++zp) {
      v2f acc;
      PK_MUL_BLO(acc, xv2[xi*2+0], Wf2[0*2+zp]);      // y=0 (lo)
      PK_FMA_BHI_ACC(acc, xv2[xi*2+0], Wf2[1*2+zp]);  // y=1 (hi)
      PK_FMA_BLO_ACC(acc, xv2[xi*2+1], Wf2[2*2+zp]);  // y=2 (lo)
      PK_FMA_BHI_ACC(acc, xv2[xi*2+1], Wf2[3*2+zp]);  // y=3 (hi)
      V2[xi*2+zp] = acc;
    }
  }
}

// ---- stats kernel: one block per (pos, half), 384 threads (6 waves).
// partial layout per block: [0..511] S1(p*32+o), [512..1023] S2, [1024..1055] rs(o)
__global__ __launch_bounds__(384, 5) void caps_stats(
    const float* __restrict__ X, const float* __restrict__ A, const float* __restrict__ Wt,
    const float* __restrict__ Bu, const float* __restrict__ Ba,
    const float* __restrict__ prev, float* __restrict__ cur, int it)
{
  __shared__ float xp_s[144*16];   // half-patch poses            9216 B
  __shared__ float a_s[144];       // half-patch activations       576 B
  __shared__ float part[6*544];    // per-wave partials, 2-phase 13056 B
  __shared__ float prs[6*32];      // per-wave sum Ra              768 B
  __shared__ float mu_t[512], isig_t[512], lsig_t[512];        // 6144 B
  __shared__ float la_s[32], slog_s[32], rs_s[32];             //  384 B

  const int t    = threadIdx.x;
  const int o    = t & 31;
  const int ng   = t >> 5;        // 0..11
  const int wv   = t >> 6;        // 0..5
  const int lane = t & 63;

  const int bid  = blockIdx.x;
  const int pos  = bid >> 1;
  const int half = bid & 1;
  const int b  = pos / 144;
  const int r_ = pos - b*144;
  const int h  = r_ / 12;
  const int w  = r_ - (r_/12)*12;
  const int nbase = half * 144;

  // ---- stage this half's 144 pose rows + activations
  for (int i = t; i < 576; i += 384) {       // 576 float4 chunks
    const int r  = i >> 2, q4 = i & 3;
    const int n  = nbase + r;
    const int kl = n >> 5, c = n & 31;
    const int hy = h + kl/3, wx = w + (kl - (kl/3)*3);
    const float4 v = *(const float4*)(X + ((((b*14+hy)*14+wx) << 9) + (c << 4) + (q4 << 2)));
    *(float4*)(xp_s + (r << 4) + (q4 << 2)) = v;
  }
  if (t < 144) {
    const int n  = nbase + t;
    const int kl = n >> 5, c = n & 31;
    const int hy = h + kl/3, wx = w + (kl - (kl/3)*3);
    a_s[t] = A[((b*14+hy)*14+wx)*32 + c];
  }

  v2f mmu2[8], isig2[8];           // pairs over p (p=2pp, 2pp+1); mmu = -mu
  float la_r = 0.f, slog_r = 0.f;

  if (it > 0) {
    // ---- recompute routing state from prev partials (both halves)
    {
      const float* h0 = prev + (pos*2+0)*1056;
      const float* h1 = prev + (pos*2+1)*1056;
      for (int idx = t; idx < 512; idx += 384) {
        const int oo = idx & 31;
        const float s1   = h0[idx]       + h1[idx];
        const float s2   = h0[512+idx]   + h1[512+idx];
        const float rsum = h0[1024+oo]   + h1[1024+oo] + EPSV;
        const float mu = s1 / rsum;
        float var = s2 / rsum - mu*mu;
        var = fmaxf(var, 0.f);
        const float sg = var + EPSV;
        mu_t[idx]   = mu;
        isig_t[idx] = 1.0f / sg;
        lsig_t[idx] = __logf(sg);
        if (idx < 32) rs_s[idx] = rsum;
      }
    }
    __syncthreads();                        // also covers staging
    if (t < 32) {
      float slog = 0.f;
#pragma unroll
      for (int p = 0; p < 16; ++p) slog += lsig_t[p*32 + t];
      const float cost = rs_s[t] * (16.0f*Bu[t] + 0.5f*slog);
      const float av = 1.0f / (1.0f + __expf(-(Ba[t] - cost)));   // LAM=1
      la_s[t]   = __logf(av + EPSV);
      slog_s[t] = slog;
    }
    __syncthreads();
#pragma unroll
    for (int pp = 0; pp < 8; ++pp) {
      mmu2[pp]  = (v2f){ -mu_t[(2*pp)*32 + o],  -mu_t[(2*pp+1)*32 + o] };
      isig2[pp] = (v2f){ isig_t[(2*pp)*32 + o], isig_t[(2*pp+1)*32 + o] };
    }
    slog_r = slog_s[o];
    la_r   = la_s[o];
  } else {
#pragma unroll
    for (int pp = 0; pp < 8; ++pp) { mmu2[pp] = (v2f)0.f; isig2[pp] = (v2f)0.f; }
    __syncthreads();                        // staging visibility
  }

  // ---- fused stats pass over this half's n's (12 j x 12 ng = 144)
  v2f S1_2[8], S2_2[8];
#pragma unroll
  for (int pp = 0; pp < 8; ++pp) { S1_2[pp] = (v2f)0.f; S2_2[pp] = (v2f)0.f; }
  float rs = 0.f;

#pragma unroll 1
  for (int j = 0; j < 12; ++j) {
    const int nl = ng + j*12;               // local row 0..143
    const int n  = nbase + nl;              // global n for W
    v2f V2[8];
    compute_votes_pk(Wt, xp_s + (nl << 4), n, o, V2);

    float ra;
    if (it == 0) {
      ra = a_s[nl] * (1.0f/32.0f);
    } else {
      v2f q2[4];
#pragma unroll
      for (int pp = 0; pp < 8; ++pp) {
        v2f d2, dd;
        PK_ADD(d2, V2[pp], mmu2[pp]);       // d = V - mu   (mmu = -mu)
        PK_MUL(dd, d2, d2);
        if (pp < 4) { PK_MUL(q2[pp], dd, isig2[pp]); }
        else        { PK_FMA_ACC(q2[pp-4], dd, isig2[pp]); }
      }
      v2f qa, qb;
      PK_ADD(qa, q2[0], q2[1]);
      PK_ADD(qb, q2[2], q2[3]);
      PK_ADD(qa, qa, qb);
      const float q = slog_r + (qa.x + qa.y);
      const float z = la_r - 0.5f*q;
      const float m  = red_max32(z);
      const float ev = __expf(z - m);
      const float s  = red_sum32(ev);
      ra = (ev / s) * a_s[nl];
    }
    rs += ra;
    {
      v2f raP = { ra, ra };
#pragma unroll
      for (int pp = 0; pp < 8; ++pp) {
        PK_FMA_ACC(S1_2[pp], raP, V2[pp]);  // S1 += ra*V
        v2f vv;
        PK_MUL(vv, V2[pp], V2[pp]);
        PK_FMA_ACC(S2_2[pp], raP, vv);      // S2 += ra*V*V
      }
    }
  }

  // ---- unpack pairs, pair-combine ng via lane^32
  float S1[16], S2[16];
#pragma unroll
  for (int pp = 0; pp < 8; ++pp) {
    S1[2*pp] = S1_2[pp].x; S1[2*pp+1] = S1_2[pp].y;
    S2[2*pp] = S2_2[pp].x; S2[2*pp+1] = S2_2[pp].y;
  }
#pragma unroll
  for (int p = 0; p < 16; ++p) {
    S1[p] += __shfl_xor(S1[p], 32);
    S2[p] += __shfl_xor(S2[p], 32);
  }
  rs += __shfl_xor(rs, 32);

  float* dst = cur + bid*1056;

  // ---- phase A: S1 partials -> global (6-wave reduce)
  if (lane < 32) {
    float* p1 = part + wv*544 + o*17;
#pragma unroll
    for (int p = 0; p < 16; ++p) p1[p] = S1[p];
    prs[wv*32 + o] = rs;
  }
  __syncthreads();
  {
    for (int idx = t; idx < 512; idx += 384) {
      const int pi = idx >> 5, oo = idx & 31;
      float s1 = 0.f;
#pragma unroll
      for (int g = 0; g < 6; ++g) s1 += part[g*544 + oo*17 + pi];
      dst[idx] = s1;                        // S1 at [0..511]
    }
    if (t < 32) {
      float r = 0.f;
#pragma unroll
      for (int g = 0; g < 6; ++g) r += prs[(g << 5) + t];
      dst[1024 + t] = r;                    // rs at [1024..1055]
    }
  }
  __syncthreads();

  // ---- phase B: S2 partials -> global
  if (lane < 32) {
    float* p2 = part + wv*544 + o*17;
#pragma unroll
    for (int p = 0; p < 16; ++p) p2[p] = S2[p];
  }
  __syncthreads();
  {
    for (int idx = t; idx < 512; idx += 384) {
      const int pi = idx >> 5, oo = idx & 31;
      float s2 = 0.f;
#pragma unroll
      for (int g = 0; g < 6; ++g) s2 += part[g*544 + oo*17 + pi];
      dst[512 + idx] = s2;                  // S2 at [512..1023]
    }
  }
}

// ---- final kernel: mu/aout from last stats partials -> Out
__global__ __launch_bounds__(512, 4) void caps_final(
    const float* __restrict__ prev, const float* __restrict__ Bu,
    const float* __restrict__ Ba, float* __restrict__ Out)
{
  __shared__ float mu_t[512], lsig_t[512], rs_s[32], aout_s[32];

  const int t   = threadIdx.x;
  const int pos = blockIdx.x;
  {
    const int pi = t >> 5, oo = t & 31;
    const float* h0 = prev + (pos*2+0)*1056;
    const float* h1 = prev + (pos*2+1)*1056;
    const int idx = pi*32 + oo;
    const float s1   = h0[idx]     + h1[idx];
    const float s2   = h0[512+idx] + h1[512+idx];
    const float rsum = h0[1024+oo] + h1[1024+oo] + EPSV;
    const float mu = s1 / rsum;
    float var = s2 / rsum - mu*mu;
    var = fmaxf(var, 0.f);
    mu_t[idx]   = mu;
    lsig_t[idx] = __logf(var + EPSV);
    if (pi == 0) rs_s[oo] = rsum;
  }
  __syncthreads();
  if (t < 32) {
    float slog = 0.f;
#pragma unroll
    for (int p = 0; p < 16; ++p) slog += lsig_t[p*32 + t];
    const float cost = rs_s[t] * (16.0f*Bu[t] + 0.5f*slog);
    aout_s[t] = 1.0f / (1.0f + __expf(-(Ba[t] - cost)));
  }
  __syncthreads();
  {
    const int oo = t >> 4, pi = t & 15;
    Out[pos*512 + t] = mu_t[pi*32 + oo];
  }
  if (t < 32) Out[294912 + pos*32 + t] = aout_s[t];
}

extern "C" void kernel_launch(void* const* d_in, const int* in_sizes, int n_in,
                              void* d_out, int out_size, void* d_ws, size_t ws_size,
                              hipStream_t stream) {
  (void)in_sizes; (void)n_in; (void)ws_size; (void)out_size;
  const float* X  = (const float*)d_in[0];
  const float* A  = (const float*)d_in[1];
  const float* Wt = (const float*)d_in[2];
  const float* Bu = (const float*)d_in[3];
  const float* Ba = (const float*)d_in[4];
  float* Out = (float*)d_out;

  float* pa = (float*)d_ws;                 // parity A: 1152*1056 floats
  float* pb = pa + 1152*1056;               // parity B (total ~9.3 MB)

  hipLaunchKernelGGL(caps_stats, dim3(1152), dim3(384), 0, stream,
                     X, A, Wt, Bu, Ba, (const float*)nullptr, pa, 0);
  hipLaunchKernelGGL(caps_stats, dim3(1152), dim3(384), 0, stream,
                     X, A, Wt, Bu, Ba, pa, pb, 1);
  hipLaunchKernelGGL(caps_stats, dim3(1152), dim3(384), 0, stream,
                     X, A, Wt, Bu, Ba, pb, pa, 2);
  hipLaunchKernelGGL(caps_final, dim3(576), dim3(512), 0, stream,
                     pa, Bu, Ba, Out);
}

// Round 9
// 185.552 us; speedup vs baseline: 1.5810x; 1.5810x over previous
//
#include <hip/hip_runtime.h>

// ConvCapsMatrix EM routing, MI355X. Inputs FP32, output FP32.
// R26: dual-half block with SHARED accumulators. One block per pos (576x512);
// each lane runs TWO independent chains per j (nA=nl half0, nB=nl+144 half1)
// that accumulate into the SAME S1/S2 (sums are per (o,p), n-independent) and
// share mu/isig/la/slog state. Chains/CU stays 32 (16 waves x 2 chains vs
// R21's 32x1) but per-wave MLP doubles (2 W-loads in flight) and each chain's
// exp/reduce latency hides under the other's VALU work. Partials complete
// per-pos -> partial traffic + next-launch state recompute HALVED; epilogue
// once per pos. j-body numerics = R21 (pk, swz16 reduce) - known-good.
// Post-mortem R25: permlane32_swap path failed correctness (absmax 445) for
// causes not diagnosable offline (index maps verified consistent) -> dropped;
// swz16 reduction restored. Register plan: S1/S2(32)+V2A/B(32)+state(16)+
// transients(~25) ~ 110 < 128 cap at (512,2). VGPR>64 EXPECTED this round
// (waves halve, chains double). Occupancy ~15-17% EXPECTED.
// GUARDRAIL: WRITE_SIZE ~2.4MB/stats launch; tens of MB => spills => abort.

#define EPSV 1e-8f

typedef float v2f __attribute__((ext_vector_type(2)));
typedef float v4f __attribute__((ext_vector_type(4)));

// packed 2xf32 ops (VOP3P). Default modifiers = normal packed lanes.
#define PK_ADD(d, a, b) asm("v_pk_add_f32 %0, %1, %2" : "=v"(d) : "v"(a), "v"(b))
#define PK_MUL(d, a, b) asm("v_pk_mul_f32 %0, %1, %2" : "=v"(d) : "v"(a), "v"(b))
#define PK_FMA_ACC(acc, a, b) \
  asm("v_pk_fma_f32 %0, %1, %2, %0" : "+v"(acc) : "v"(a), "v"(b))
// src0 broadcast from lo / hi dword of the pair (op_sel per-src dword select)
#define PK_MUL_BLO(d, a, b) \
  asm("v_pk_mul_f32 %0, %1, %2 op_sel:[0,0] op_sel_hi:[0,1]" : "=v"(d) : "v"(a), "v"(b))
#define PK_FMA_BLO_ACC(acc, a, b) \
  asm("v_pk_fma_f32 %0, %1, %2, %0 op_sel:[0,0,0] op_sel_hi:[0,1,1]" : "+v"(acc) : "v"(a), "v"(b))
#define PK_FMA_BHI_ACC(acc, a, b) \
  asm("v_pk_fma_f32 %0, %1, %2, %0 op_sel:[1,0,0] op_sel_hi:[1,1,1]" : "+v"(acc) : "v"(a), "v"(b))

template <int CTRL>
__device__ __forceinline__ float dppf(float v) {
  return __int_as_float(__builtin_amdgcn_update_dpp(
      0, __float_as_int(v), CTRL, 0xf, 0xf, true));
}
__device__ __forceinline__ float swz16(float v) {   // lane ^ 16 within 32-groups
  return __int_as_float(__builtin_amdgcn_ds_swizzle(__float_as_int(v), 0x401F));
}
__device__ __forceinline__ float red_max32(float v) {
  v = fmaxf(v, dppf<0xB1>(v));
  v = fmaxf(v, dppf<0x4E>(v));
  v = fmaxf(v, dppf<0x141>(v));
  v = fmaxf(v, dppf<0x140>(v));
  v = fmaxf(v, swz16(v));
  return v;
}
__device__ __forceinline__ float red_sum32(float v) {
  v += dppf<0xB1>(v);
  v += dppf<0x4E>(v);
  v += dppf<0x141>(v);
  v += dppf<0x140>(v);
  v += swz16(v);
  return v;
}

// V2[xi*2+zp] lanes (z=2zp, 2zp+1) = sum_y xv[xi*4+y] * Wf[y*4+z]
__device__ __forceinline__ void compute_votes_pk(const float* __restrict__ Wt,
                                                 const float* __restrict__ xr,
                                                 int n, int o, v2f* __restrict__ V2)
{
  v2f Wf2[8];
  {
    const float* wp = Wt + (((n << 5) + o) << 4);
#pragma unroll
    for (int i = 0; i < 4; ++i) {
      const v4f q = *(const v4f*)(wp + (i << 2));
      Wf2[i*2+0] = __builtin_shufflevector(q, q, 0, 1);
      Wf2[i*2+1] = __builtin_shufflevector(q, q, 2, 3);
    }
  }
  v2f xv2[8];
#pragma unroll
  for (int i = 0; i < 4; ++i) {
    const v4f q = *(const v4f*)(xr + (i << 2));
    xv2[i*2+0] = __builtin_shufflevector(q, q, 0, 1);
    xv2[i*2+1] = __builtin_shufflevector(q, q, 2, 3);
  }
#pragma unroll
  for (int xi = 0; xi < 4; ++xi) {
#pragma unroll
    for (int zp = 0; zp < 2; ++zp) {
      v2f acc;
      PK_MUL_BLO(acc, xv2[xi*2+0], Wf2[0*2+zp]);      // y=0 (lo)
      PK_FMA_BHI_ACC(acc, xv2[xi*2+0], Wf2[1*2+zp]);  // y=1 (hi)
      PK_FMA_BLO_ACC(acc, xv2[xi*2+1], Wf2[2*2+zp]);  // y=2 (lo)
      PK_FMA_BHI_ACC(acc, xv2[xi*2+1], Wf2[3*2+zp]);  // y=3 (hi)
      V2[xi*2+zp] = acc;
    }
  }
}

// ---- stats kernel: one block per pos (BOTH halves). Writes per-pos partials.
// partial layout per pos: [0..511] S1(p*32+o), [512..1023] S2, [1024..1055] rs(o)
__global__ __launch_bounds__(512, 2) void caps_stats(
    const float* __restrict__ X, const float* __restrict__ A, const float* __restrict__ Wt,
    const float* __restrict__ Bu, const float* __restrict__ Ba,
    const float* __restrict__ prev, float* __restrict__ cur, int it)
{
  __shared__ float xp_s[288*16];   // all 288 pose rows          18432 B
  __shared__ float a_s[288];       // activations                 1152 B
  __shared__ float part[8*544];    // per-wave partials, 2-phase 17408 B
  __shared__ float prs[8*32];      // per-wave sum Ra             1024 B
  __shared__ float mu_t[512], isig_t[512], lsig_t[512];        // 6144 B
  __shared__ float la_s[32], slog_s[32], rs_s[32];             //  384 B

  const int t    = threadIdx.x;
  const int o    = t & 31;
  const int ng   = t >> 5;        // 0..15
  const int wv   = t >> 6;        // 0..7
  const int lane = t & 63;

  const int pos = blockIdx.x;
  const int b  = pos / 144;
  const int r_ = pos - b*144;
  const int h  = r_ / 12;
  const int w  = r_ - (r_/12)*12;

  // ---- stage ALL 288 pose rows + activations
  for (int i = t; i < 1152; i += 512) {      // 1152 float4 chunks
    const int r  = i >> 2, q4 = i & 3;
    const int kl = r >> 5, c = r & 31;
    const int hy = h + kl/3, wx = w + (kl - (kl/3)*3);
    const float4 v = *(const float4*)(X + ((((b*14+hy)*14+wx) << 9) + (c << 4) + (q4 << 2)));
    *(float4*)(xp_s + (r << 4) + (q4 << 2)) = v;
  }
  if (t < 288) {
    const int kl = t >> 5, c = t & 31;
    const int hy = h + kl/3, wx = w + (kl - (kl/3)*3);
    a_s[t] = A[((b*14+hy)*14+wx)*32 + c];
  }

  v2f mmu2[8], isig2[8];           // pairs over p (p=2pp, 2pp+1); mmu = -mu
  float la_r = 0.f, slog_r = 0.f;

  if (it > 0) {
    // ---- recompute routing state from prev per-pos partials
    {
      const int pi = t >> 5, oo = t & 31;
      const float* hp = prev + (size_t)pos * 1056;
      const int idx = pi*32 + oo;
      const float s1   = hp[idx];
      const float s2   = hp[512+idx];
      const float rsum = hp[1024+oo] + EPSV;
      const float mu = s1 / rsum;
      float var = s2 / rsum - mu*mu;
      var = fmaxf(var, 0.f);
      const float sg = var + EPSV;
      mu_t[idx]   = mu;
      isig_t[idx] = 1.0f / sg;
      lsig_t[idx] = __logf(sg);
      if (pi == 0) rs_s[oo] = rsum;
    }
    __syncthreads();                        // also covers staging
    if (t < 32) {
      float slog = 0.f;
#pragma unroll
      for (int p = 0; p < 16; ++p) slog += lsig_t[p*32 + t];
      const float cost = rs_s[t] * (16.0f*Bu[t] + 0.5f*slog);
      const float av = 1.0f / (1.0f + __expf(-(Ba[t] - cost)));   // LAM=1
      la_s[t]   = __logf(av + EPSV);
      slog_s[t] = slog;
    }
    __syncthreads();
#pragma unroll
    for (int pp = 0; pp < 8; ++pp) {
      mmu2[pp]  = (v2f){ -mu_t[(2*pp)*32 + o],  -mu_t[(2*pp+1)*32 + o] };
      isig2[pp] = (v2f){ isig_t[(2*pp)*32 + o], isig_t[(2*pp+1)*32 + o] };
    }
    slog_r = slog_s[o];
    la_r   = la_s[o];
  } else {
#pragma unroll
    for (int pp = 0; pp < 8; ++pp) { mmu2[pp] = (v2f)0.f; isig2[pp] = (v2f)0.f; }
    __syncthreads();                        // staging visibility
  }

  // ---- fused stats pass: per j, TWO chains (nA = nl, nB = nl+144)
  v2f S1_2[8], S2_2[8];                     // SHARED accumulators (per o,p)
#pragma unroll
  for (int pp = 0; pp < 8; ++pp) { S1_2[pp] = (v2f)0.f; S2_2[pp] = (v2f)0.f; }
  float rs = 0.f;

#pragma unroll 1
  for (int j = 0; j < 9; ++j) {
    const int nl = ng + (j << 4);           // 0..143
    v2f VA[8], VB[8];
    compute_votes_pk(Wt, xp_s + (nl << 4),         nl,       o, VA);
    compute_votes_pk(Wt, xp_s + ((nl + 144) << 4), nl + 144, o, VB);

    float raA, raB;
    if (it == 0) {
      raA = a_s[nl]       * (1.0f/32.0f);
      raB = a_s[nl + 144] * (1.0f/32.0f);
    } else {
      v2f qA2[4], qB2[4];
#pragma unroll
      for (int pp = 0; pp < 8; ++pp) {
        v2f d2, dd;
        PK_ADD(d2, VA[pp], mmu2[pp]);  PK_MUL(dd, d2, d2);
        if (pp < 4) { PK_MUL(qA2[pp], dd, isig2[pp]); }
        else        { PK_FMA_ACC(qA2[pp-4], dd, isig2[pp]); }
        PK_ADD(d2, VB[pp], mmu2[pp]);  PK_MUL(dd, d2, d2);
        if (pp < 4) { PK_MUL(qB2[pp], dd, isig2[pp]); }
        else        { PK_FMA_ACC(qB2[pp-4], dd, isig2[pp]); }
      }
      v2f qa, qb;
      PK_ADD(qa, qA2[0], qA2[1]);  PK_ADD(qb, qA2[2], qA2[3]);  PK_ADD(qa, qa, qb);
      const float qA = slog_r + (qa.x + qa.y);
      PK_ADD(qa, qB2[0], qB2[1]);  PK_ADD(qb, qB2[2], qB2[3]);  PK_ADD(qa, qa, qb);
      const float qB = slog_r + (qa.x + qa.y);
      const float zA = la_r - 0.5f*qA;
      const float zB = la_r - 0.5f*qB;
      const float mA  = red_max32(zA);
      const float mB  = red_max32(zB);
      const float evA = __expf(zA - mA);
      const float evB = __expf(zB - mB);
      const float sA  = red_sum32(evA);
      const float sB  = red_sum32(evB);
      raA = (evA / sA) * a_s[nl];
      raB = (evB / sB) * a_s[nl + 144];
    }
    rs += raA + raB;
    {
      v2f rA = { raA, raA }, rB = { raB, raB };
#pragma unroll
      for (int pp = 0; pp < 8; ++pp) {
        PK_FMA_ACC(S1_2[pp], rA, VA[pp]);   // S1 += raA*VA
        v2f vv;
        PK_MUL(vv, VA[pp], VA[pp]);
        PK_FMA_ACC(S2_2[pp], rA, vv);       // S2 += raA*VA^2
        PK_FMA_ACC(S1_2[pp], rB, VB[pp]);   // S1 += raB*VB
        PK_MUL(vv, VB[pp], VB[pp]);
        PK_FMA_ACC(S2_2[pp], rB, vv);       // S2 += raB*VB^2
      }
    }
  }

  // ---- unpack pairs, pair-combine ng via lane^32
  float S1[16], S2[16];
#pragma unroll
  for (int pp = 0; pp < 8; ++pp) {
    S1[2*pp] = S1_2[pp].x; S1[2*pp+1] = S1_2[pp].y;
    S2[2*pp] = S2_2[pp].x; S2[2*pp+1] = S2_2[pp].y;
  }
#pragma unroll
  for (int p = 0; p < 16; ++p) {
    S1[p] += __shfl_xor(S1[p], 32);
    S2[p] += __shfl_xor(S2[p], 32);
  }
  rs += __shfl_xor(rs, 32);

  float* dst = cur + (size_t)pos * 1056;

  // ---- phase A: S1 partials -> global (full-pos sums)
  if (lane < 32) {
    float* p1 = part + wv*544 + o*17;
#pragma unroll
    for (int p = 0; p < 16; ++p) p1[p] = S1[p];
    prs[wv*32 + o] = rs;
  }
  __syncthreads();
  {
    const int pi = t >> 5, oo = t & 31;
    float s1 = 0.f;
#pragma unroll
    for (int g = 0; g < 8; ++g) s1 += part[g*544 + oo*17 + pi];
    dst[t] = s1;                            // S1 at [0..511]
    if (t < 32) {
      float r = 0.f;
#pragma unroll
      for (int g = 0; g < 8; ++g) r += prs[(g << 5) + t];
      dst[1024 + t] = r;                    // rs at [1024..1055]
    }
  }
  __syncthreads();

  // ---- phase B: S2 partials -> global
  if (lane < 32) {
    float* p2 = part + wv*544 + o*17;
#pragma unroll
    for (int p = 0; p < 16; ++p) p2[p] = S2[p];
  }
  __syncthreads();
  {
    const int pi = t >> 5, oo = t & 31;
    float s2 = 0.f;
#pragma unroll
    for (int g = 0; g < 8; ++g) s2 += part[g*544 + oo*17 + pi];
    dst[512 + t] = s2;                      // S2 at [512..1023]
  }
}

// ---- final kernel: mu/aout from last per-pos partials -> Out
__global__ __launch_bounds__(512, 4) void caps_final(
    const float* __restrict__ prev, const float* __restrict__ Bu,
    const float* __restrict__ Ba, float* __restrict__ Out)
{
  __shared__ float mu_t[512], lsig_t[512], rs_s[32], aout_s[32];

  const int t   = threadIdx.x;
  const int pos = blockIdx.x;
  {
    const int pi = t >> 5, oo = t & 31;
    const float* hp = prev + (size_t)pos * 1056;
    const int idx = pi*32 + oo;
    const float s1   = hp[idx];
    const float s2   = hp[512+idx];
    const float rsum = hp[1024+oo] + EPSV;
    const float mu = s1 / rsum;
    float var = s2 / rsum - mu*mu;
    var = fmaxf(var, 0.f);
    mu_t[idx]   = mu;
    lsig_t[idx] = __logf(var + EPSV);
    if (pi == 0) rs_s[oo] = rsum;
  }
  __syncthreads();
  if (t < 32) {
    float slog = 0.f;
#pragma unroll
    for (int p = 0; p < 16; ++p) slog += lsig_t[p*32 + t];
    const float cost = rs_s[t] * (16.0f*Bu[t] + 0.5f*slog);
    aout_s[t] = 1.0f / (1.0f + __expf(-(Ba[t] - cost)));
  }
  __syncthreads();
  {
    const int oo = t >> 4, pi = t & 15;
    Out[pos*512 + t] = mu_t[pi*32 + oo];
  }
  if (t < 32) Out[294912 + pos*32 + t] = aout_s[t];
}

extern "C" void kernel_launch(void* const* d_in, const int* in_sizes, int n_in,
                              void* d_out, int out_size, void* d_ws, size_t ws_size,
                              hipStream_t stream) {
  (void)in_sizes; (void)n_in; (void)ws_size; (void)out_size;
  const float* X  = (const float*)d_in[0];
  const float* A  = (const float*)d_in[1];
  const float* Wt = (const float*)d_in[2];
  const float* Bu = (const float*)d_in[3];
  const float* Ba = (const float*)d_in[4];
  float* Out = (float*)d_out;

  float* pa = (float*)d_ws;                 // parity A: 576*1056 floats (~2.4MB)
  float* pb = pa + 576*1056;                // parity B

  hipLaunchKernelGGL(caps_stats, dim3(576), dim3(512), 0, stream,
                     X, A, Wt, Bu, Ba, (const float*)nullptr, pa, 0);
  hipLaunchKernelGGL(caps_stats, dim3(576), dim3(512), 0, stream,
                     X, A, Wt, Bu, Ba, pa, pb, 1);
  hipLaunchKernelGGL(caps_stats, dim3(576), dim3(512), 0, stream,
                     X, A, Wt, Bu, Ba, pb, pa, 2);
  hipLaunchKernelGGL(caps_final, dim3(576), dim3(512), 0, stream,
                     pa, Bu, Ba, Out);
}

// Round 10
// 159.045 us; speedup vs baseline: 1.8445x; 1.1667x over previous
//
#include <hip/hip_runtime.h>

// ConvCapsMatrix EM routing, MI355X. Inputs FP32, output FP32.
// R27: CHAMPION RESTORE = R21 verbatim (best measured: 160.1us wall, absmax
// 0.0078125, stats <41.3us/launch, VGPR 64 -> 4 blocks/CU, 32 waves/CU).
// Nine-round falsification matrix (all measured):
//   wave ladder: 32 waves = 38.5-41.5us | 16 waves = 51.7us (R23 AND R26,
//   identical despite different ILP mechanisms) | spilling = 101-116us.
//   - issue count: pk cut 40% of j-body instrs -> -3% (R21). Not issue-bound.
//   - wave supply: 3x finer grid -> worse (R19b). Fixed cost ~ 1 j-iter/block.
//   - launch fusion: per-pos single kernel -> 137us kernel, worse (R22).
//   - reg prefetch: VGPR 68 -> 16 waves -> 51.7us (R23). TLP loss > ILP gain.
//   - launch_bounds: any cap below natural use -> scratch spills (R20/R24).
//   - permlane32_swap softmax: correctness failure, dropped (R25).
//   - intra-wave dual chains, shared acc: VGPR 88, no spills, 51.7us (R26).
//     ILP == TLP at fixed chains/CU; stall is a shared per-CU resource
//     (W-load L2 latency/queueing: ~4000cyc/j wall vs ~940cyc chain).
// Conclusion: 64-VGPR/32-wave/4-launch split is the optimum of this space.
// The j-body MUST stay <=64 VGPR (the 32-wave bracket). Do not unroll the
// j-loop; do not add live state across compute_votes_pk.

#define EPSV 1e-8f

typedef float v2f __attribute__((ext_vector_type(2)));
typedef float v4f __attribute__((ext_vector_type(4)));

// packed 2xf32 ops (VOP3P). Default modifiers = normal packed lanes.
#define PK_ADD(d, a, b) asm("v_pk_add_f32 %0, %1, %2" : "=v"(d) : "v"(a), "v"(b))
#define PK_MUL(d, a, b) asm("v_pk_mul_f32 %0, %1, %2" : "=v"(d) : "v"(a), "v"(b))
#define PK_FMA_ACC(acc, a, b) \
  asm("v_pk_fma_f32 %0, %1, %2, %0" : "+v"(acc) : "v"(a), "v"(b))
// src0 broadcast from lo / hi dword of the pair (op_sel per-src dword select)
#define PK_MUL_BLO(d, a, b) \
  asm("v_pk_mul_f32 %0, %1, %2 op_sel:[0,0] op_sel_hi:[0,1]" : "=v"(d) : "v"(a), "v"(b))
#define PK_FMA_BLO_ACC(acc, a, b) \
  asm("v_pk_fma_f32 %0, %1, %2, %0 op_sel:[0,0,0] op_sel_hi:[0,1,1]" : "+v"(acc) : "v"(a), "v"(b))
#define PK_FMA_BHI_ACC(acc, a, b) \
  asm("v_pk_fma_f32 %0, %1, %2, %0 op_sel:[1,0,0] op_sel_hi:[1,1,1]" : "+v"(acc) : "v"(a), "v"(b))

template <int CTRL>
__device__ __forceinline__ float dppf(float v) {
  return __int_as_float(__builtin_amdgcn_update_dpp(
      0, __float_as_int(v), CTRL, 0xf, 0xf, true));
}
__device__ __forceinline__ float swz16(float v) {   // lane ^ 16 within 32-groups
  return __int_as_float(__builtin_amdgcn_ds_swizzle(__float_as_int(v), 0x401F));
}
__device__ __forceinline__ float red_max32(float v) {
  v = fmaxf(v, dppf<0xB1>(v));
  v = fmaxf(v, dppf<0x4E>(v));
  v = fmaxf(v, dppf<0x141>(v));
  v = fmaxf(v, dppf<0x140>(v));
  v = fmaxf(v, swz16(v));
  return v;
}
__device__ __forceinline__ float red_sum32(float v) {
  v += dppf<0xB1>(v);
  v += dppf<0x4E>(v);
  v += dppf<0x141>(v);
  v += dppf<0x140>(v);
  v += swz16(v);
  return v;
}

// V2[xi*2+zp] lanes (z=2zp, 2zp+1) = sum_y xv[xi*4+y] * Wf[y*4+z]
__device__ __forceinline__ void compute_votes_pk(const float* __restrict__ Wt,
                                                 const float* __restrict__ xr,
                                                 int n, int o, v2f* __restrict__ V2)
{
  v2f Wf2[8];
  {
    const float* wp = Wt + (((n << 5) + o) << 4);
#pragma unroll
    for (int i = 0; i < 4; ++i) {
      const v4f q = *(const v4f*)(wp + (i << 2));
      Wf2[i*2+0] = __builtin_shufflevector(q, q, 0, 1);
      Wf2[i*2+1] = __builtin_shufflevector(q, q, 2, 3);
    }
  }
  v2f xv2[8];
#pragma unroll
  for (int i = 0; i < 4; ++i) {
    const v4f q = *(const v4f*)(xr + (i << 2));
    xv2[i*2+0] = __builtin_shufflevector(q, q, 0, 1);
    xv2[i*2+1] = __builtin_shufflevector(q, q, 2, 3);
  }
#pragma unroll
  for (int xi = 0; xi < 4; ++xi) {
#pragma unroll
    for (int zp = 0; zp < 2; ++zp) {
      v2f acc;
      PK_MUL_BLO(acc, xv2[xi*2+0], Wf2[0*2+zp]);      // y=0 (lo)
      PK_FMA_BHI_ACC(acc, xv2[xi*2+0], Wf2[1*2+zp]);  // y=1 (hi)
      PK_FMA_BLO_ACC(acc, xv2[xi*2+1], Wf2[2*2+zp]);  // y=2 (lo)
      PK_FMA_BHI_ACC(acc, xv2[xi*2+1], Wf2[3*2+zp]);  // y=3 (hi)
      V2[xi*2+zp] = acc;
    }
  }
}

// ---- stats kernel: one block per (pos, half). Writes partials to cur.
// partial layout per block: [0..511] S1(p*32+o), [512..1023] S2, [1024..1055] rs(o)
__global__ __launch_bounds__(512, 2) void caps_stats(
    const float* __restrict__ X, const float* __restrict__ A, const float* __restrict__ Wt,
    const float* __restrict__ Bu, const float* __restrict__ Ba,
    const float* __restrict__ prev, float* __restrict__ cur, int it)
{
  __shared__ float xp_s[144*16];   // half-patch poses            9216 B
  __shared__ float a_s[144];       // half-patch activations       576 B
  __shared__ float part[8*544];    // per-wave partials, 2-phase 17408 B
  __shared__ float prs[8*32];      // per-wave sum Ra             1024 B
  __shared__ float mu_t[512], isig_t[512], lsig_t[512];        // 6144 B
  __shared__ float la_s[32], slog_s[32], rs_s[32];

  const int t    = threadIdx.x;
  const int o    = t & 31;
  const int ng   = t >> 5;        // 0..15
  const int wv   = t >> 6;        // 0..7
  const int lane = t & 63;

  const int bid  = blockIdx.x;
  const int pos  = bid >> 1;
  const int half = bid & 1;
  const int b  = pos / 144;
  const int r_ = pos - b*144;
  const int h  = r_ / 12;
  const int w  = r_ - (r_/12)*12;
  const int nbase = half * 144;

  // ---- stage this half's 144 pose rows + activations
  for (int i = t; i < 576; i += 512) {       // 576 float4 chunks
    const int r  = i >> 2, q4 = i & 3;
    const int n  = nbase + r;
    const int kl = n >> 5, c = n & 31;
    const int hy = h + kl/3, wx = w + (kl - (kl/3)*3);
    const float4 v = *(const float4*)(X + ((((b*14+hy)*14+wx) << 9) + (c << 4) + (q4 << 2)));
    *(float4*)(xp_s + (r << 4) + (q4 << 2)) = v;
  }
  if (t < 144) {
    const int n  = nbase + t;
    const int kl = n >> 5, c = n & 31;
    const int hy = h + kl/3, wx = w + (kl - (kl/3)*3);
    a_s[t] = A[((b*14+hy)*14+wx)*32 + c];
  }

  v2f mmu2[8], isig2[8];           // pairs over p (p=2pp, 2pp+1); mmu = -mu
  float la_r = 0.f, slog_r = 0.f;

  if (it > 0) {
    // ---- recompute routing state from prev partials (both halves)
    {
      const int pi = t >> 5, oo = t & 31;
      const float* h0 = prev + (pos*2+0)*1056;
      const float* h1 = prev + (pos*2+1)*1056;
      const int idx = pi*32 + oo;
      const float s1   = h0[idx]       + h1[idx];
      const float s2   = h0[512+idx]   + h1[512+idx];
      const float rsum = h0[1024+oo]   + h1[1024+oo] + EPSV;
      const float mu = s1 / rsum;
      float var = s2 / rsum - mu*mu;
      var = fmaxf(var, 0.f);
      const float sg = var + EPSV;
      mu_t[idx]   = mu;
      isig_t[idx] = 1.0f / sg;
      lsig_t[idx] = __logf(sg);
      if (pi == 0) rs_s[oo] = rsum;
    }
    __syncthreads();                        // also covers staging
    if (t < 32) {
      float slog = 0.f;
#pragma unroll
      for (int p = 0; p < 16; ++p) slog += lsig_t[p*32 + t];
      const float cost = rs_s[t] * (16.0f*Bu[t] + 0.5f*slog);
      const float av = 1.0f / (1.0f + __expf(-(Ba[t] - cost)));   // LAM=1
      la_s[t]   = __logf(av + EPSV);
      slog_s[t] = slog;
    }
    __syncthreads();
#pragma unroll
    for (int pp = 0; pp < 8; ++pp) {
      mmu2[pp]  = (v2f){ -mu_t[(2*pp)*32 + o],  -mu_t[(2*pp+1)*32 + o] };
      isig2[pp] = (v2f){ isig_t[(2*pp)*32 + o], isig_t[(2*pp+1)*32 + o] };
    }
    slog_r = slog_s[o];
    la_r   = la_s[o];
  } else {
#pragma unroll
    for (int pp = 0; pp < 8; ++pp) { mmu2[pp] = (v2f)0.f; isig2[pp] = (v2f)0.f; }
    __syncthreads();                        // staging visibility
  }

  // ---- fused stats pass over this half's n's
  v2f S1_2[8], S2_2[8];
#pragma unroll
  for (int pp = 0; pp < 8; ++pp) { S1_2[pp] = (v2f)0.f; S2_2[pp] = (v2f)0.f; }
  float rs = 0.f;

#pragma unroll 1
  for (int j = 0; j < 9; ++j) {
    const int nl = ng + (j << 4);           // local row 0..143
    const int n  = nbase + nl;              // global n for W
    v2f V2[8];
    compute_votes_pk(Wt, xp_s + (nl << 4), n, o, V2);

    float ra;
    if (it == 0) {
      ra = a_s[nl] * (1.0f/32.0f);
    } else {
      v2f q2[4];
#pragma unroll
      for (int pp = 0; pp < 8; ++pp) {
        v2f d2, dd;
        PK_ADD(d2, V2[pp], mmu2[pp]);       // d = V - mu   (mmu = -mu)
        PK_MUL(dd, d2, d2);
        if (pp < 4) { PK_MUL(q2[pp], dd, isig2[pp]); }
        else        { PK_FMA_ACC(q2[pp-4], dd, isig2[pp]); }
      }
      v2f qa, qb;
      PK_ADD(qa, q2[0], q2[1]);
      PK_ADD(qb, q2[2], q2[3]);
      PK_ADD(qa, qa, qb);
      const float q = slog_r + (qa.x + qa.y);
      const float z = la_r - 0.5f*q;
      const float m  = red_max32(z);
      const float ev = __expf(z - m);
      const float s  = red_sum32(ev);
      ra = (ev / s) * a_s[nl];
    }
    rs += ra;
    {
      v2f raP = { ra, ra };
#pragma unroll
      for (int pp = 0; pp < 8; ++pp) {
        PK_FMA_ACC(S1_2[pp], raP, V2[pp]);  // S1 += ra*V
        v2f vv;
        PK_MUL(vv, V2[pp], V2[pp]);
        PK_FMA_ACC(S2_2[pp], raP, vv);      // S2 += ra*V*V
      }
    }
  }

  // ---- unpack pairs, pair-combine ng via lane^32
  float S1[16], S2[16];
#pragma unroll
  for (int pp = 0; pp < 8; ++pp) {
    S1[2*pp] = S1_2[pp].x; S1[2*pp+1] = S1_2[pp].y;
    S2[2*pp] = S2_2[pp].x; S2[2*pp+1] = S2_2[pp].y;
  }
#pragma unroll
  for (int p = 0; p < 16; ++p) {
    S1[p] += __shfl_xor(S1[p], 32);
    S2[p] += __shfl_xor(S2[p], 32);
  }
  rs += __shfl_xor(rs, 32);

  float* dst = cur + bid*1056;

  // ---- phase A: S1 partials -> global
  if (lane < 32) {
    float* p1 = part + wv*544 + o*17;
#pragma unroll
    for (int p = 0; p < 16; ++p) p1[p] = S1[p];
    prs[wv*32 + o] = rs;
  }
  __syncthreads();
  {
    const int pi = t >> 5, oo = t & 31;
    float s1 = 0.f;
#pragma unroll
    for (int g = 0; g < 8; ++g) s1 += part[g*544 + oo*17 + pi];
    dst[t] = s1;                            // S1 at [0..511]
    if (t < 32) {
      float r = 0.f;
#pragma unroll
      for (int g = 0; g < 8; ++g) r += prs[(g << 5) + t];
      dst[1024 + t] = r;                    // rs at [1024..1055]
    }
  }
  __syncthreads();

  // ---- phase B: S2 partials -> global
  if (lane < 32) {
    float* p2 = part + wv*544 + o*17;
#pragma unroll
    for (int p = 0; p < 16; ++p) p2[p] = S2[p];
  }
  __syncthreads();
  {
    const int pi = t >> 5, oo = t & 31;
    float s2 = 0.f;
#pragma unroll
    for (int g = 0; g < 8; ++g) s2 += part[g*544 + oo*17 + pi];
    dst[512 + t] = s2;                      // S2 at [512..1023]
  }
}

// ---- final kernel: mu/aout from last stats partials -> Out
__global__ __launch_bounds__(512, 4) void caps_final(
    const float* __restrict__ prev, const float* __restrict__ Bu,
    const float* __restrict__ Ba, float* __restrict__ Out)
{
  __shared__ float mu_t[512], lsig_t[512], rs_s[32], aout_s[32];

  const int t   = threadIdx.x;
  const int pos = blockIdx.x;
  {
    const int pi = t >> 5, oo = t & 31;
    const float* h0 = prev + (pos*2+0)*1056;
    const float* h1 = prev + (pos*2+1)*1056;
    const int idx = pi*32 + oo;
    const float s1   = h0[idx]     + h1[idx];
    const float s2   = h0[512+idx] + h1[512+idx];
    const float rsum = h0[1024+oo] + h1[1024+oo] + EPSV;
    const float mu = s1 / rsum;
    float var = s2 / rsum - mu*mu;
    var = fmaxf(var, 0.f);
    mu_t[idx]   = mu;
    lsig_t[idx] = __logf(var + EPSV);
    if (pi == 0) rs_s[oo] = rsum;
  }
  __syncthreads();
  if (t < 32) {
    float slog = 0.f;
#pragma unroll
    for (int p = 0; p < 16; ++p) slog += lsig_t[p*32 + t];
    const float cost = rs_s[t] * (16.0f*Bu[t] + 0.5f*slog);
    aout_s[t] = 1.0f / (1.0f + __expf(-(Ba[t] - cost)));
  }
  __syncthreads();
  {
    const int oo = t >> 4, pi = t & 15;
    Out[pos*512 + t] = mu_t[pi*32 + oo];
  }
  if (t < 32) Out[294912 + pos*32 + t] = aout_s[t];
}

extern "C" void kernel_launch(void* const* d_in, const int* in_sizes, int n_in,
                              void* d_out, int out_size, void* d_ws, size_t ws_size,
                              hipStream_t stream) {
  (void)in_sizes; (void)n_in; (void)ws_size; (void)out_size;
  const float* X  = (const float*)d_in[0];
  const float* A  = (const float*)d_in[1];
  const float* Wt = (const float*)d_in[2];
  const float* Bu = (const float*)d_in[3];
  const float* Ba = (const float*)d_in[4];
  float* Out = (float*)d_out;

  float* pa = (float*)d_ws;                 // parity A: 1152*1056 floats
  float* pb = pa + 1152*1056;               // parity B (total ~9.3 MB)

  hipLaunchKernelGGL(caps_stats, dim3(1152), dim3(512), 0, stream,
                     X, A, Wt, Bu, Ba, (const float*)nullptr, pa, 0);
  hipLaunchKernelGGL(caps_stats, dim3(1152), dim3(512), 0, stream,
                     X, A, Wt, Bu, Ba, pa, pb, 1);
  hipLaunchKernelGGL(caps_stats, dim3(1152), dim3(512), 0, stream,
                     X, A, Wt, Bu, Ba, pb, pa, 2);
  hipLaunchKernelGGL(caps_final, dim3(576), dim3(512), 0, stream,
                     pa, Bu, Ba, Out);
}